// Round 1
// baseline (230.699 us; speedup 1.0000x reference)
//
#include <hip/hip_runtime.h>
#include <math.h>

// ---------------------------------------------------------------------------
// ScatteringNetwork:
//   img [8,1,256,256] f32, psi_re/psi_im [10,1,11,11] f32, blur_k [7,7] f32
//   out: concat([s0(1ch), s1_out(10ch), s2_out(100ch)]) at 32x32 -> [8, 111*1024]
//
// Key trick: blur(conv(x,psi))[::8] == conv(x, psi (*) blur)[::8]  (17x17
// combined kernel, only 32x32 output positions). Exact except where blur's
// zero-pad clips at output index 0 per axis -> 4 precomputed clip-variants +
// a tiny border-fix kernel for the 63 border pixels per channel.
//
// ws layout (floats):
//   [0)              s1abs  : 8*10*256*256 = 5,242,880
//   [5242880)        combT  : 4 variants * 289 taps * 10 ch = 11,560
//                              combT[v*2890 + (i*17+j)*10 + k]
//   [5254440)        psit   : 121 taps * 20 (re/im interleaved per ch) = 2,420
// total ~21.03 MB
// ---------------------------------------------------------------------------

#define S1ABS_OFF 0
#define COMBT_OFF 5242880
#define PSIT_OFF  5254440

// combined kernel: c_v[k][i][j] = sum_{p,q in clip-set} blur[p][q]*psi[k][i-p][j-q]
__global__ void k_comb(const float* __restrict__ psi_re,
                       const float* __restrict__ blur,
                       float* __restrict__ combT) {
    int idx = blockIdx.x * 256 + threadIdx.x;
    if (idx >= 4 * 289 * 10) return;
    int k = idx % 10;
    int t = idx / 10;
    int ij = t % 289;
    int v = t / 289;
    int i = ij / 17, j = ij % 17;
    int pmin = (v & 2) ? 3 : 0;   // row-clip (Y==0)
    int qmin = (v & 1) ? 3 : 0;   // col-clip (X==0)
    float s = 0.f;
    for (int p = pmin; p < 7; ++p) {
        int ii = i - p; if (ii < 0 || ii >= 11) continue;
        for (int q = qmin; q < 7; ++q) {
            int jj = j - q; if (jj < 0 || jj >= 11) continue;
            s += blur[p * 7 + q] * psi_re[k * 121 + ii * 11 + jj];
        }
    }
    combT[v * 2890 + ij * 10 + k] = s;
}

// transpose psi into [tap][20] (re,im interleaved per channel) for scalar loads
__global__ void k_psit(const float* __restrict__ psi_re,
                       const float* __restrict__ psi_im,
                       float* __restrict__ psit) {
    int idx = blockIdx.x * 256 + threadIdx.x;
    if (idx >= 121 * 20) return;
    int c2 = idx % 20, uv = idx / 20;
    int c = c2 >> 1;
    psit[idx] = (c2 & 1) ? psi_im[c * 121 + uv] : psi_re[c * 121 + uv];
}

// full-res |s1| = sqrt(conv_re^2 + conv_im^2), tiled 16x16 with LDS halo
__global__ __launch_bounds__(256) void k_s1abs(const float* __restrict__ img,
                                               const float* __restrict__ psit,
                                               float* __restrict__ s1abs) {
    __shared__ float tile[26][27];   // +1 pad stride
    int n = blockIdx.z;
    int y0 = blockIdx.y * 16, x0 = blockIdx.x * 16;
    int tx = threadIdx.x, ty = threadIdx.y;
    int tid = ty * 16 + tx;
    const float* im = img + n * 65536;
    for (int t = tid; t < 26 * 26; t += 256) {
        int r = t / 26, c = t - r * 26;
        int gy = y0 + r - 5, gx = x0 + c - 5;
        tile[r][c] = (gy >= 0 && gy < 256 && gx >= 0 && gx < 256) ? im[gy * 256 + gx] : 0.f;
    }
    __syncthreads();
    float ar[10], ai[10];
#pragma unroll
    for (int c = 0; c < 10; ++c) { ar[c] = 0.f; ai[c] = 0.f; }
    for (int u = 0; u < 11; ++u) {
#pragma unroll
        for (int vv = 0; vv < 11; ++vv) {
            float x = tile[ty + u][tx + vv];
            const float* pw = psit + (u * 11 + vv) * 20;  // wave-uniform -> s_load
#pragma unroll
            for (int c = 0; c < 10; ++c) {
                ar[c] = fmaf(x, pw[2 * c], ar[c]);
                ai[c] = fmaf(x, pw[2 * c + 1], ai[c]);
            }
        }
    }
    float* ob = s1abs + (size_t)(n * 10) * 65536 + (y0 + ty) * 256 + (x0 + tx);
#pragma unroll
    for (int c = 0; c < 10; ++c)
        ob[c * 65536] = sqrtf(ar[c] * ar[c] + ai[c] * ai[c]);
}

// s0 (direct clipped blur) + s1_out (composed 17x17, variant 0; borders fixed later)
__global__ __launch_bounds__(256) void k_s0s1(const float* __restrict__ img,
                                              const float* __restrict__ blur,
                                              const float* __restrict__ combT,
                                              float* __restrict__ out) {
    int gid = blockIdx.x * 256 + threadIdx.x;   // 8*1024 total
    int n = gid >> 10;
    int p = gid & 1023;
    int Y = p >> 5, X = p & 31;
    const float* im = img + n * 65536;

    float s0 = 0.f;
    for (int p7 = 0; p7 < 7; ++p7) {
        int r = 8 * Y + p7 - 3; if (r < 0 || r >= 256) continue;
        for (int q7 = 0; q7 < 7; ++q7) {
            int c = 8 * X + q7 - 3; if (c < 0 || c >= 256) continue;
            s0 += blur[p7 * 7 + q7] * im[r * 256 + c];
        }
    }
    float acc[10];
#pragma unroll
    for (int k = 0; k < 10; ++k) acc[k] = 0.f;
    for (int i = 0; i < 17; ++i) {
        int r = 8 * Y + i - 8;
        bool rok = (r >= 0 && r < 256);
        for (int j = 0; j < 17; ++j) {
            int c = 8 * X + j - 8;
            float x = (rok && c >= 0 && c < 256) ? im[r * 256 + c] : 0.f;
            const float* cb = combT + (i * 17 + j) * 10;   // uniform -> s_load
#pragma unroll
            for (int k = 0; k < 10; ++k) acc[k] = fmaf(x, cb[k], acc[k]);
        }
    }
    float* ob = out + (size_t)n * 111 * 1024 + Y * 32 + X;
    ob[0] = s0;
#pragma unroll
    for (int k = 0; k < 10; ++k) ob[(1 + k) * 1024] = acc[k];
}

// s2_out: composed 17x17 conv of s1abs (group g -> 10 output channels), variant 0
__global__ __launch_bounds__(256) void k_s2(const float* __restrict__ s1abs,
                                            const float* __restrict__ combT,
                                            float* __restrict__ out) {
    int n = blockIdx.z, g = blockIdx.y, yt = blockIdx.x;
    int tid = threadIdx.x;
    int X = tid & 31, ty = tid >> 5;
    int Y = yt * 8 + ty;
    const float* in = s1abs + (size_t)(n * 10 + g) * 65536;
    float acc[10];
#pragma unroll
    for (int k = 0; k < 10; ++k) acc[k] = 0.f;
    for (int i = 0; i < 17; ++i) {
        int r = 8 * Y + i - 8;
        bool rok = (r >= 0 && r < 256);
        for (int j = 0; j < 17; ++j) {
            int c = 8 * X + j - 8;
            float x = (rok && c >= 0 && c < 256) ? in[r * 256 + c] : 0.f;
            const float* cb = combT + (i * 17 + j) * 10;   // uniform -> s_load
#pragma unroll
            for (int k = 0; k < 10; ++k) acc[k] = fmaf(x, cb[k], acc[k]);
        }
    }
    float* ob = out + (size_t)n * 111 * 1024 + (size_t)(11 + g * 10) * 1024 + Y * 32 + X;
#pragma unroll
    for (int k = 0; k < 10; ++k) ob[k * 1024] = acc[k];
}

// overwrite the 63 border pixels (Y==0 or X==0) of every s1/s2 channel with the
// correct clip-variant combined kernel
__global__ void k_fix(const float* __restrict__ img,
                      const float* __restrict__ s1abs,
                      const float* __restrict__ combT,
                      float* __restrict__ out) {
    int idx = blockIdx.x * 256 + threadIdx.x;
    if (idx >= 8 * 110 * 63) return;
    int b = idx % 63;
    int t = idx / 63;
    int c = t % 110 + 1;       // channels 1..110
    int n = t / 110;
    int Y, X;
    if (b < 32) { Y = 0; X = b; } else { Y = b - 31; X = 0; }
    int v = ((Y == 0) ? 2 : 0) | ((X == 0) ? 1 : 0);
    const float* in;
    int k;
    if (c < 11) { in = img + n * 65536; k = c - 1; }
    else {
        int c2 = c - 11;
        int g = c2 / 10;
        k = c2 - g * 10;
        in = s1abs + (size_t)(n * 10 + g) * 65536;
    }
    const float* cb = combT + v * 2890 + k;
    float acc = 0.f;
    for (int i = 0; i < 17; ++i) {
        int r = 8 * Y + i - 8; if (r < 0 || r >= 256) continue;
        for (int j = 0; j < 17; ++j) {
            int cc = 8 * X + j - 8; if (cc < 0 || cc >= 256) continue;
            acc = fmaf(in[r * 256 + cc], cb[(i * 17 + j) * 10], acc);
        }
    }
    out[(size_t)n * 111 * 1024 + (size_t)c * 1024 + Y * 32 + X] = acc;
}

extern "C" void kernel_launch(void* const* d_in, const int* in_sizes, int n_in,
                              void* d_out, int out_size, void* d_ws, size_t ws_size,
                              hipStream_t stream) {
    const float* img    = (const float*)d_in[0];
    const float* psi_re = (const float*)d_in[1];
    const float* psi_im = (const float*)d_in[2];
    const float* blur   = (const float*)d_in[3];
    float* out = (float*)d_out;
    float* ws = (float*)d_ws;
    float* s1abs = ws + S1ABS_OFF;
    float* combT = ws + COMBT_OFF;
    float* psit  = ws + PSIT_OFF;

    k_comb<<<(4 * 289 * 10 + 255) / 256, 256, 0, stream>>>(psi_re, blur, combT);
    k_psit<<<(121 * 20 + 255) / 256, 256, 0, stream>>>(psi_re, psi_im, psit);

    dim3 gA(16, 16, 8), bA(16, 16);
    k_s1abs<<<gA, bA, 0, stream>>>(img, psit, s1abs);

    k_s0s1<<<32, 256, 0, stream>>>(img, blur, combT, out);

    dim3 gC(4, 10, 8);
    k_s2<<<gC, 256, 0, stream>>>(s1abs, combT, out);

    k_fix<<<(8 * 110 * 63 + 255) / 256, 256, 0, stream>>>(img, s1abs, combT, out);
}

// Round 2
// 106.968 us; speedup vs baseline: 2.1567x; 2.1567x over previous
//
#include <hip/hip_runtime.h>
#include <math.h>

// ---------------------------------------------------------------------------
// ScatteringNetwork:
//   img [8,1,256,256] f32, psi_re/psi_im [10,1,11,11] f32, blur_k [7,7] f32
//   out: concat([s0(1ch), s1_out(10ch), s2_out(100ch)]) at 32x32 -> [8, 111*1024]
//
// blur(conv(x,psi))[::8] == conv(x, psi (*) blur)[::8]  (17x17 combined kernel
// at 32x32 positions). Exact except blur zero-pad clipping at Y==0 / X==0 ->
// 4 clip-variants; border pixels fixed by k_fix2.
//
// k_main: one block = (4 Y-rows x 32 X) x one source channel (img or one s1abs
// channel) x one batch. Input window staged in LDS in phase-decomposed layout
// [41 rows][8 phases][35 cols/8] so stride-8 tap reads are lane-consecutive
// (bank-conflict-free). Weights via wave-uniform s_load.
//
// ws layout (floats):
//   [0)        s1abs : 8*10*256*256 = 5,242,880
//   [5242880)  combT : 4 variants * 289 taps * 10 ch = 11,560
//   [5254440)  psit  : 121 taps * 20 = 2,420
// ---------------------------------------------------------------------------

#define S1ABS_OFF 0
#define COMBT_OFF 5242880
#define PSIT_OFF  5254440

__global__ void k_comb(const float* __restrict__ psi_re,
                       const float* __restrict__ blur,
                       float* __restrict__ combT) {
    int idx = blockIdx.x * 256 + threadIdx.x;
    if (idx >= 4 * 289 * 10) return;
    int k = idx % 10;
    int t = idx / 10;
    int ij = t % 289;
    int v = t / 289;
    int i = ij / 17, j = ij % 17;
    int pmin = (v & 2) ? 3 : 0;
    int qmin = (v & 1) ? 3 : 0;
    float s = 0.f;
    for (int p = pmin; p < 7; ++p) {
        int ii = i - p; if (ii < 0 || ii >= 11) continue;
        for (int q = qmin; q < 7; ++q) {
            int jj = j - q; if (jj < 0 || jj >= 11) continue;
            s += blur[p * 7 + q] * psi_re[k * 121 + ii * 11 + jj];
        }
    }
    combT[v * 2890 + ij * 10 + k] = s;
}

__global__ void k_psit(const float* __restrict__ psi_re,
                       const float* __restrict__ psi_im,
                       float* __restrict__ psit) {
    int idx = blockIdx.x * 256 + threadIdx.x;
    if (idx >= 121 * 20) return;
    int c2 = idx % 20, uv = idx / 20;
    int c = c2 >> 1;
    psit[idx] = (c2 & 1) ? psi_im[c * 121 + uv] : psi_re[c * 121 + uv];
}

// full-res |s1| = sqrt(conv_re^2 + conv_im^2), 16x16 tile with LDS halo
__global__ __launch_bounds__(256) void k_s1abs(const float* __restrict__ img,
                                               const float* __restrict__ psit,
                                               float* __restrict__ s1abs) {
    __shared__ float tile[26][27];
    int n = blockIdx.z;
    int y0 = blockIdx.y * 16, x0 = blockIdx.x * 16;
    int tx = threadIdx.x, ty = threadIdx.y;
    int tid = ty * 16 + tx;
    const float* im = img + n * 65536;
    for (int t = tid; t < 26 * 26; t += 256) {
        int r = t / 26, c = t - r * 26;
        int gy = y0 + r - 5, gx = x0 + c - 5;
        tile[r][c] = (gy >= 0 && gy < 256 && gx >= 0 && gx < 256) ? im[gy * 256 + gx] : 0.f;
    }
    __syncthreads();
    float ar[10], ai[10];
#pragma unroll
    for (int c = 0; c < 10; ++c) { ar[c] = 0.f; ai[c] = 0.f; }
    for (int u = 0; u < 11; ++u) {
#pragma unroll
        for (int vv = 0; vv < 11; ++vv) {
            float x = tile[ty + u][tx + vv];
            const float* pw = psit + (u * 11 + vv) * 20;  // uniform -> s_load
#pragma unroll
            for (int c = 0; c < 10; ++c) {
                ar[c] = fmaf(x, pw[2 * c], ar[c]);
                ai[c] = fmaf(x, pw[2 * c + 1], ai[c]);
            }
        }
    }
    float* ob = s1abs + (size_t)(n * 10) * 65536 + (y0 + ty) * 256 + (x0 + tx);
#pragma unroll
    for (int c = 0; c < 10; ++c)
        ob[c * 65536] = sqrtf(ar[c] * ar[c] + ai[c] * ai[c]);
}

// unified composed-conv kernel: grid (8 ybands, 11 src, 8 n), 256 threads.
// src 0 -> img: writes ch 0 (s0, exact blur) + ch 1..10 (s1_out, variant 0)
// src g+1 -> s1abs[g]: writes ch 11+10g .. 20+10g (variant 0)
__global__ __launch_bounds__(256) void k_main(const float* __restrict__ img,
                                              const float* __restrict__ s1abs,
                                              const float* __restrict__ combT,
                                              const float* __restrict__ blur,
                                              float* __restrict__ out) {
    __shared__ float tile[41 * 280];   // [41 rows][8 phases][35]
    int tid = threadIdx.x;
    int bx = blockIdx.x;          // y-band: Y in 4*bx .. 4*bx+3
    int src = blockIdx.y;         // 0..10
    int n = blockIdx.z;

    const float* sp = (src == 0) ? img + n * 65536
                                 : s1abs + (size_t)(n * 10 + src - 1) * 65536;
    int base_r = 32 * bx - 8;
    for (int idx = tid; idx < 41 * 273; idx += 256) {
        int r = idx / 273, cc = idx - r * 273;
        int gr = base_r + r, gc = cc - 8;
        float v = 0.f;
        if (gr >= 0 && gr < 256 && gc >= 0 && gc < 256) v = sp[gr * 256 + gc];
        tile[r * 280 + (cc & 7) * 35 + (cc >> 3)] = v;
    }
    __syncthreads();

    int X = tid & 31;
    int t2 = tid >> 5;
    int y = t2 & 3;
    int half_u = __builtin_amdgcn_readfirstlane(t2 >> 2);  // wave-uniform -> SGPR
    int Y = 4 * bx + y;

    float acc[5] = {0.f, 0.f, 0.f, 0.f, 0.f};
    const float* cb0 = combT + half_u * 5;
    for (int i = 0; i < 17; ++i) {
        int vb = (8 * y + i) * 280 + X;
        const float* cbi = cb0 + i * 170;
#pragma unroll
        for (int j = 0; j < 17; ++j) {
            float x = tile[vb + (j & 7) * 35 + (j >> 3)];
            const float* cw = cbi + j * 10;
#pragma unroll
            for (int kk = 0; kk < 5; ++kk)
                acc[kk] = fmaf(x, cw[kk], acc[kk]);
        }
    }

    size_t nb = (size_t)n * 111 * 1024;
    int ch0 = (src == 0) ? 1 : 11 + (src - 1) * 10;
    float* ob = out + nb + (size_t)(ch0 + half_u * 5) * 1024 + Y * 32 + X;
#pragma unroll
    for (int kk = 0; kk < 5; ++kk) ob[kk * 1024] = acc[kk];

    if (src == 0 && half_u == 0) {   // wave-uniform branch: s0 = clipped blur
        float s0 = 0.f;
        for (int p = 0; p < 7; ++p) {
            int rb = (8 * y + p + 5) * 280 + X;
#pragma unroll
            for (int q = 0; q < 7; ++q) {
                int cc = q + 5;
                float x = tile[rb + (cc & 7) * 35 + (cc >> 3)];
                s0 = fmaf(blur[p * 7 + q], x, s0);
            }
        }
        out[nb + Y * 32 + X] = s0;
    }
}

// border fix: one output per 32-lane half-wave; 289 taps split across lanes
__global__ __launch_bounds__(256) void k_fix2(const float* __restrict__ img,
                                              const float* __restrict__ s1abs,
                                              const float* __restrict__ combT,
                                              float* __restrict__ out) {
    int gid = blockIdx.x * 8 + (threadIdx.x >> 5);   // output id, < 55440
    int lane = threadIdx.x & 31;
    int b = gid % 63;
    int t = gid / 63;
    int c = t % 110 + 1;
    int n = t / 110;
    int Y, X;
    if (b < 32) { Y = 0; X = b; } else { Y = b - 31; X = 0; }
    int v = ((Y == 0) ? 2 : 0) | ((X == 0) ? 1 : 0);
    const float* in;
    int k;
    if (c < 11) { in = img + n * 65536; k = c - 1; }
    else {
        int c2 = c - 11;
        int g = c2 / 10;
        k = c2 - g * 10;
        in = s1abs + (size_t)(n * 10 + g) * 65536;
    }
    const float* cw = combT + v * 2890 + k;
    float acc = 0.f;
    for (int m = 0; m < 10; ++m) {
        int t9 = lane + 32 * m;
        if (t9 >= 289) break;
        int i = t9 / 17, j = t9 - i * 17;
        int r = 8 * Y + i - 8, cc = 8 * X + j - 8;
        float x = (r >= 0 && r < 256 && cc >= 0 && cc < 256) ? in[r * 256 + cc] : 0.f;
        acc = fmaf(x, cw[t9 * 10], acc);
    }
#pragma unroll
    for (int mask = 16; mask >= 1; mask >>= 1)
        acc += __shfl_xor(acc, mask);
    if (lane == 0)
        out[((size_t)n * 111 + c) * 1024 + Y * 32 + X] = acc;
}

extern "C" void kernel_launch(void* const* d_in, const int* in_sizes, int n_in,
                              void* d_out, int out_size, void* d_ws, size_t ws_size,
                              hipStream_t stream) {
    const float* img    = (const float*)d_in[0];
    const float* psi_re = (const float*)d_in[1];
    const float* psi_im = (const float*)d_in[2];
    const float* blur   = (const float*)d_in[3];
    float* out = (float*)d_out;
    float* ws = (float*)d_ws;
    float* s1abs = ws + S1ABS_OFF;
    float* combT = ws + COMBT_OFF;
    float* psit  = ws + PSIT_OFF;

    k_comb<<<(4 * 289 * 10 + 255) / 256, 256, 0, stream>>>(psi_re, blur, combT);
    k_psit<<<(121 * 20 + 255) / 256, 256, 0, stream>>>(psi_re, psi_im, psit);

    dim3 gA(16, 16, 8), bA(16, 16);
    k_s1abs<<<gA, bA, 0, stream>>>(img, psit, s1abs);

    dim3 gM(8, 11, 8);
    k_main<<<gM, 256, 0, stream>>>(img, s1abs, combT, blur, out);

    k_fix2<<<6930, 256, 0, stream>>>(img, s1abs, combT, out);
}

// Round 3
// 87.315 us; speedup vs baseline: 2.6421x; 1.2251x over previous
//
#include <hip/hip_runtime.h>
#include <math.h>

// ---------------------------------------------------------------------------
// ScatteringNetwork:
//   img [8,1,256,256] f32, psi_re/psi_im [10,1,11,11] f32, blur_k [7,7] f32
//   out: concat([s0(1ch), s1_out(10ch), s2_out(100ch)]) at 32x32 -> [8, 111*1024]
//
// blur(conv(x,psi))[::8] == conv(x, psi (*) blur)[::8]  (17x17 combined kernel
// at 32x32 positions), 4 clip-variants for the Y==0/X==0 blur-pad edge,
// borders fixed by k_fix2.
//
// Morlet bank is rank-1 separable: psi[i][j] = F_i * H_j (complex), recovered
// numerically as F_i = psi[i][5]/psi[5][5], H_j = psi[5][j]. |s1| kernel
// (k_s1sep) = row pass (real x complex, 22 FMA/tap-ch) into LDS + col pass
// (complex x complex) with 4-way y-blocking and wave-uniform channels.
//
// ws layout (floats):
//   [0)        s1abs : 8*10*256*256 = 5,242,880
//   [5242880)  combT : 4 variants * 289 taps * 10 ch = 11,560
//   [5254440)  fh    : Hw[10][11][2] + Fw[10][11][2] = 440
// ---------------------------------------------------------------------------

#define S1ABS_OFF 0
#define COMBT_OFF 5242880
#define FH_OFF    5254440

__global__ void k_comb(const float* __restrict__ psi_re,
                       const float* __restrict__ blur,
                       float* __restrict__ combT) {
    int idx = blockIdx.x * 256 + threadIdx.x;
    if (idx >= 4 * 289 * 10) return;
    int k = idx % 10;
    int t = idx / 10;
    int ij = t % 289;
    int v = t / 289;
    int i = ij / 17, j = ij % 17;
    int pmin = (v & 2) ? 3 : 0;
    int qmin = (v & 1) ? 3 : 0;
    float s = 0.f;
    for (int p = pmin; p < 7; ++p) {
        int ii = i - p; if (ii < 0 || ii >= 11) continue;
        for (int q = qmin; q < 7; ++q) {
            int jj = j - q; if (jj < 0 || jj >= 11) continue;
            s += blur[p * 7 + q] * psi_re[k * 121 + ii * 11 + jj];
        }
    }
    combT[v * 2890 + ij * 10 + k] = s;
}

// separable factors: F_i = psi[i][5]/psi[5][5], H_j = psi[5][j]  (complex)
__global__ void k_fh(const float* __restrict__ psi_re,
                     const float* __restrict__ psi_im,
                     float* __restrict__ fh) {
    int t = threadIdx.x;
    if (t >= 110) return;
    int k = t / 11, i = t - k * 11;
    const float* pr = psi_re + k * 121;
    const float* pi = psi_im + k * 121;
    float hr = pr[55 + i], hi = pi[55 + i];
    float nr = pr[i * 11 + 5], ni = pi[i * 11 + 5];
    float dr = pr[60], di = pi[60];
    float inv = 1.f / (dr * dr + di * di);
    fh[(k * 11 + i) * 2]       = hr;                       // Hw
    fh[(k * 11 + i) * 2 + 1]   = hi;
    fh[220 + (k * 11 + i) * 2]     = (nr * dr + ni * di) * inv;  // Fw
    fh[220 + (k * 11 + i) * 2 + 1] = (ni * dr - nr * di) * inv;
}

#define TSTR 27
#define ISTR 34            // words per inter row (16 complex + pad), even -> b64
#define ICH  (26 * ISTR)   // 884 floats per channel

// |s1| via separable complex conv. grid (16,16,8), block 256.
// wave = chq (0..3): channels {chq, chq+4[, chq+8]}; lanes = (x, yq).
__global__ __launch_bounds__(256) void k_s1sep(const float* __restrict__ img,
                                               const float* __restrict__ fh,
                                               float* __restrict__ s1abs) {
    __shared__ float lds[26 * TSTR + 10 * ICH];   // 702 + 8840 = 38.2 KB
    float* timg = lds;
    float* inter = lds + 26 * TSTR;
    int n = blockIdx.z;
    int y0 = blockIdx.y * 16, x0 = blockIdx.x * 16;
    int tid = threadIdx.x;
    const float* im = img + n * 65536;
    for (int idx = tid; idx < 26 * 26; idx += 256) {
        int r = idx / 26, c = idx - r * 26;
        int gy = y0 + r - 5, gx = x0 + c - 5;
        timg[r * TSTR + c] = (gy >= 0 && gy < 256 && gx >= 0 && gx < 256) ? im[gy * 256 + gx] : 0.f;
    }
    __syncthreads();

    int lane = tid & 63;
    int chq = __builtin_amdgcn_readfirstlane(tid >> 6);   // wave index -> SGPR
    int nch = (chq < 2) ? 3 : 2;
    const float* Hw = fh;
    const float* Fw = fh + 220;

    // row pass: Y_c(r,cx) = sum_j H_c(j) * timg[r][cx+j]
    for (int p = lane; p < 416; p += 64) {
        int r = p >> 4, cx = p & 15;
        float xv[11];
#pragma unroll
        for (int j = 0; j < 11; ++j) xv[j] = timg[r * TSTR + cx + j];
#pragma unroll
        for (int q = 0; q < 3; ++q) {
            if (q >= nch) break;                 // wave-uniform
            int c = chq + 4 * q;
            const float* h = Hw + c * 22;        // uniform -> s_load
            float ar = 0.f, ai = 0.f;
#pragma unroll
            for (int j = 0; j < 11; ++j) {
                ar = fmaf(xv[j], h[2 * j], ar);
                ai = fmaf(xv[j], h[2 * j + 1], ai);
            }
            float* dst = inter + c * ICH + r * ISTR + 2 * cx;
            dst[0] = ar; dst[1] = ai;            // b64 write (8B aligned)
        }
    }
    __syncthreads();

    // col pass: out(y,x,c) = | sum_i F_c(i) * Y_c(y+i, x) |, 4 y's per thread
    int x = tid & 15, yq = (tid >> 4) & 3;
    int ybase = 4 * yq;
    for (int q = 0; q < 3; ++q) {
        if (q >= nch) break;                     // wave-uniform
        int c = chq + 4 * q;
        const float* f = Fw + c * 22;            // uniform -> s_load
        const float* src = inter + c * ICH + ybase * ISTR + 2 * x;
        float accr[4] = {0.f, 0.f, 0.f, 0.f};
        float acci[4] = {0.f, 0.f, 0.f, 0.f};
#pragma unroll
        for (int r = 0; r < 14; ++r) {
            float vr = src[r * ISTR], vi = src[r * ISTR + 1];   // b64 read
#pragma unroll
            for (int dy = 0; dy < 4; ++dy) {
                int i = r - dy;
                if (i >= 0 && i <= 10) {
                    float fr = f[2 * i], fim = f[2 * i + 1];
                    accr[dy] = fmaf(fr, vr, fmaf(-fim, vi, accr[dy]));
                    acci[dy] = fmaf(fr, vi, fmaf(fim, vr, acci[dy]));
                }
            }
        }
        float* so = s1abs + (size_t)(n * 10 + c) * 65536 + (y0 + ybase) * 256 + x0 + x;
#pragma unroll
        for (int dy = 0; dy < 4; ++dy)
            so[dy * 256] = sqrtf(accr[dy] * accr[dy] + acci[dy] * acci[dy]);
    }
}

// unified composed-conv kernel: grid (8 ybands, 11 src, 8 n), 256 threads.
__global__ __launch_bounds__(256) void k_main(const float* __restrict__ img,
                                              const float* __restrict__ s1abs,
                                              const float* __restrict__ combT,
                                              const float* __restrict__ blur,
                                              float* __restrict__ out) {
    __shared__ float tile[41 * 280];   // [41 rows][8 phases][35]
    int tid = threadIdx.x;
    int bx = blockIdx.x;
    int src = blockIdx.y;
    int n = blockIdx.z;

    const float* sp = (src == 0) ? img + n * 65536
                                 : s1abs + (size_t)(n * 10 + src - 1) * 65536;
    int base_r = 32 * bx - 8;
    for (int idx = tid; idx < 41 * 273; idx += 256) {
        int r = idx / 273, cc = idx - r * 273;
        int gr = base_r + r, gc = cc - 8;
        float v = 0.f;
        if (gr >= 0 && gr < 256 && gc >= 0 && gc < 256) v = sp[gr * 256 + gc];
        tile[r * 280 + (cc & 7) * 35 + (cc >> 3)] = v;
    }
    __syncthreads();

    int X = tid & 31;
    int t2 = tid >> 5;
    int y = t2 & 3;
    int half_u = __builtin_amdgcn_readfirstlane(t2 >> 2);
    int Y = 4 * bx + y;

    float acc[5] = {0.f, 0.f, 0.f, 0.f, 0.f};
    const float* cb0 = combT + half_u * 5;
    for (int i = 0; i < 17; ++i) {
        int vb = (8 * y + i) * 280 + X;
        const float* cbi = cb0 + i * 170;
#pragma unroll
        for (int j = 0; j < 17; ++j) {
            float x = tile[vb + (j & 7) * 35 + (j >> 3)];
            const float* cw = cbi + j * 10;
#pragma unroll
            for (int kk = 0; kk < 5; ++kk)
                acc[kk] = fmaf(x, cw[kk], acc[kk]);
        }
    }

    size_t nb = (size_t)n * 111 * 1024;
    int ch0 = (src == 0) ? 1 : 11 + (src - 1) * 10;
    float* ob = out + nb + (size_t)(ch0 + half_u * 5) * 1024 + Y * 32 + X;
#pragma unroll
    for (int kk = 0; kk < 5; ++kk) ob[kk * 1024] = acc[kk];

    if (src == 0 && half_u == 0) {
        float s0 = 0.f;
        for (int p = 0; p < 7; ++p) {
            int rb = (8 * y + p + 5) * 280 + X;
#pragma unroll
            for (int q = 0; q < 7; ++q) {
                int cc = q + 5;
                float x = tile[rb + (cc & 7) * 35 + (cc >> 3)];
                s0 = fmaf(blur[p * 7 + q], x, s0);
            }
        }
        out[nb + Y * 32 + X] = s0;
    }
}

// border fix: one output per 32-lane half-wave
__global__ __launch_bounds__(256) void k_fix2(const float* __restrict__ img,
                                              const float* __restrict__ s1abs,
                                              const float* __restrict__ combT,
                                              float* __restrict__ out) {
    int gid = blockIdx.x * 8 + (threadIdx.x >> 5);
    int lane = threadIdx.x & 31;
    int b = gid % 63;
    int t = gid / 63;
    int c = t % 110 + 1;
    int n = t / 110;
    int Y, X;
    if (b < 32) { Y = 0; X = b; } else { Y = b - 31; X = 0; }
    int v = ((Y == 0) ? 2 : 0) | ((X == 0) ? 1 : 0);
    const float* in;
    int k;
    if (c < 11) { in = img + n * 65536; k = c - 1; }
    else {
        int c2 = c - 11;
        int g = c2 / 10;
        k = c2 - g * 10;
        in = s1abs + (size_t)(n * 10 + g) * 65536;
    }
    const float* cw = combT + v * 2890 + k;
    float acc = 0.f;
    for (int m = 0; m < 10; ++m) {
        int t9 = lane + 32 * m;
        if (t9 >= 289) break;
        int i = t9 / 17, j = t9 - i * 17;
        int r = 8 * Y + i - 8, cc = 8 * X + j - 8;
        float x = (r >= 0 && r < 256 && cc >= 0 && cc < 256) ? in[r * 256 + cc] : 0.f;
        acc = fmaf(x, cw[t9 * 10], acc);
    }
#pragma unroll
    for (int mask = 16; mask >= 1; mask >>= 1)
        acc += __shfl_xor(acc, mask);
    if (lane == 0)
        out[((size_t)n * 111 + c) * 1024 + Y * 32 + X] = acc;
}

extern "C" void kernel_launch(void* const* d_in, const int* in_sizes, int n_in,
                              void* d_out, int out_size, void* d_ws, size_t ws_size,
                              hipStream_t stream) {
    const float* img    = (const float*)d_in[0];
    const float* psi_re = (const float*)d_in[1];
    const float* psi_im = (const float*)d_in[2];
    const float* blur   = (const float*)d_in[3];
    float* out = (float*)d_out;
    float* ws = (float*)d_ws;
    float* s1abs = ws + S1ABS_OFF;
    float* combT = ws + COMBT_OFF;
    float* fh    = ws + FH_OFF;

    k_comb<<<(4 * 289 * 10 + 255) / 256, 256, 0, stream>>>(psi_re, blur, combT);
    k_fh<<<1, 128, 0, stream>>>(psi_re, psi_im, fh);

    dim3 gS(16, 16, 8);
    k_s1sep<<<gS, 256, 0, stream>>>(img, fh, s1abs);

    dim3 gM(8, 11, 8);
    k_main<<<gM, 256, 0, stream>>>(img, s1abs, combT, blur, out);

    k_fix2<<<6930, 256, 0, stream>>>(img, s1abs, combT, out);
}